// Round 9
// baseline (367.081 us; speedup 1.0000x reference)
//
#include <hip/hip_runtime.h>
#include <cstdint>

typedef __bf16 bf16_t;
typedef __bf16 bf16x8 __attribute__((ext_vector_type(8)));
typedef __bf16 bf16x4 __attribute__((ext_vector_type(4)));
typedef float  f32x4  __attribute__((ext_vector_type(4)));

// Problem constants (B=2, T=2048, C=2048, H=16, hd=128)
#define BB 2
#define TT 2048
#define CC 2048
#define HH 16
#define HD 128

static __device__ __forceinline__ void async_copy16(const void* gp, void* lp) {
  __builtin_amdgcn_global_load_lds(
      (const __attribute__((address_space(1))) void*)(uintptr_t)gp,
      (__attribute__((address_space(3))) void*)(uint32_t)(uintptr_t)lp,
      16, 0, 0);
}

// ---------------- fused cast f32 -> bf16 for x + 4 weights ----------------
__global__ __launch_bounds__(256)
void cast_all(const float* __restrict__ x, const float* __restrict__ wq,
              const float* __restrict__ wk, const float* __restrict__ wv,
              const float* __restrict__ wo, bf16_t* __restrict__ xb,
              bf16_t* __restrict__ wq_b) {
  const int NX4 = (BB * TT * CC) / 4;  // 2097152
  const int NW4 = (CC * CC) / 4;       // 1048576
  int i = blockIdx.x * 256 + threadIdx.x;
  const float* s;
  bf16_t* d;
  int off;
  if (i < NX4) {
    s = x; d = xb; off = i;
  } else {
    int j = i - NX4;
    int w = j >> 20;            // NW4 = 2^20
    off = j & (NW4 - 1);
    s = (w == 0) ? wq : (w == 1) ? wk : (w == 2) ? wv : wo;
    d = wq_b + (size_t)w * (CC * CC);
  }
  float4 v = ((const float4*)s)[off];
  bf16x4 o;
  o[0] = (bf16_t)v.x; o[1] = (bf16_t)v.y; o[2] = (bf16_t)v.z; o[3] = (bf16_t)v.w;
  ((bf16x4*)d)[off] = o;
}

// ---------------- 128x128 GEMM: V projection -> V^T [B,H,hd,T] -------------
__global__ __launch_bounds__(256)
void gemm_v(const bf16_t* __restrict__ A, const bf16_t* __restrict__ Bw,
            bf16_t* __restrict__ C2, int Kdim) {
  __shared__ __align__(16) char smem[128 * 136 * 2];  // As+Bs (32KB) / Ct (34KB)
  bf16_t* As = (bf16_t*)smem;
  bf16_t* Bs = (bf16_t*)(smem + 16384);
  const int tid  = threadIdx.x;
  const int wave = tid >> 6, lane = tid & 63;
  const int quad = lane >> 4, l16 = lane & 15;
  const int m0 = blockIdx.y * 128, n0 = blockIdx.x * 128;
  const int wm = (wave >> 1) * 64, wn = (wave & 1) * 64;

  f32x4 acc[4][4] = {};

  const int srow = lane >> 3;                       // row in 8-row chunk (=r&7)
  const int scol = (((lane & 7) ^ srow) & 7) * 8;   // swizzled source col
  const int swz  = (l16 & 7) * 8;                   // read-side xor (elements)

  for (int k0 = 0; k0 < Kdim; k0 += 64) {
#pragma unroll
    for (int i = 0; i < 4; ++i) {
      int chunk = wave * 4 + i;
      int row = chunk * 8 + srow;
      async_copy16(A + (size_t)(m0 + row) * Kdim + k0 + scol, As + chunk * 512);
    }
#pragma unroll
    for (int i = 0; i < 4; ++i) {
      int chunk = wave * 4 + i;
      int row = chunk * 8 + srow;
      async_copy16(Bw + (size_t)(n0 + row) * Kdim + k0 + scol, Bs + chunk * 512);
    }
    __syncthreads();
#pragma unroll
    for (int kk = 0; kk < 64; kk += 32) {
      const int koff = (kk + quad * 8) ^ swz;
      bf16x8 af[4], bfr[4];
#pragma unroll
      for (int i = 0; i < 4; ++i)
        af[i] = *(const bf16x8*)&As[(wm + i * 16 + l16) * 64 + koff];
#pragma unroll
      for (int j = 0; j < 4; ++j)
        bfr[j] = *(const bf16x8*)&Bs[(wn + j * 16 + l16) * 64 + koff];
#pragma unroll
      for (int i = 0; i < 4; ++i)
#pragma unroll
        for (int j = 0; j < 4; ++j)
          acc[i][j] = __builtin_amdgcn_mfma_f32_16x16x32_bf16(af[i], bfr[j], acc[i][j], 0, 0, 0);
    }
    __syncthreads();
  }

  // V: stage tile in LDS (stride 136), then coalesced writes along T
  const int h = (n0 & (CC - 1)) >> 7;
  bf16_t* Ct = (bf16_t*)smem;
  __syncthreads();
#pragma unroll
  for (int i = 0; i < 4; ++i)
#pragma unroll
    for (int j = 0; j < 4; ++j) {
      int c = wn + j * 16 + l16;
#pragma unroll
      for (int r = 0; r < 4; ++r)
        Ct[(wm + i * 16 + quad * 4 + r) * 136 + c] = (bf16_t)acc[i][j][r];
    }
  __syncthreads();
  const unsigned short* Cu = (const unsigned short*)Ct;
  int col = tid >> 1;                 // d within head: 0..127
  int rh  = (tid & 1) * 64;           // row half
  int grow0 = m0 + rh;
  int b = grow0 >> 11, t0 = grow0 & (TT - 1);
  unsigned int pk[32];
#pragma unroll
  for (int s = 0; s < 32; ++s) {
    unsigned int lo = Cu[(rh + 2 * s) * 136 + col];
    unsigned int hi = Cu[(rh + 2 * s + 1) * 136 + col];
    pk[s] = lo | (hi << 16);
  }
  bf16_t* dstp = C2 + ((size_t)(b * HH + h) * HD + col) * TT + t0;
#pragma unroll
  for (int u = 0; u < 8; ++u) {
    uint4 w; w.x = pk[4*u]; w.y = pk[4*u+1]; w.z = pk[4*u+2]; w.w = pk[4*u+3];
    *(uint4*)(dstp + 8 * u) = w;
  }
}

// ---------------- 256x256 fused QK GEMM + fused RoPE epilogue --------------
// (round-6, verified: WRITE_SIZE 32.8MB, ~71us, 968 TF)
__global__ __launch_bounds__(512, 2)
void gemm_qkv256(const bf16_t* __restrict__ A, const bf16_t* __restrict__ Bw,
                 bf16_t* __restrict__ Qo, bf16_t* __restrict__ Ko,
                 const float* __restrict__ cosT, const float* __restrict__ sinT,
                 int Kdim) {
  extern __shared__ __align__(16) char smem[];
  bf16_t* lds = (bf16_t*)smem;
  const int tid  = threadIdx.x;
  const int wave = tid >> 6, lane = tid & 63;
  const int quad = lane >> 4, l16 = lane & 15;
  const int wm = wave >> 2, wn = wave & 3;
  const int n0 = blockIdx.x * 256, m0 = blockIdx.y * 256;

  const int srow = lane >> 3;
  const int scol = ((lane & 7) ^ srow) * 8;
  const int swz  = (l16 & 7) * 8;
  const int nK = Kdim >> 6;

  const bf16_t* Ag = A  + (size_t)(m0 + wave * 32 + srow) * Kdim + scol;
  const bf16_t* Bg = Bw + (size_t)(n0 + wave * 32 + srow) * Kdim + scol;
  const int ldsChunk = wave * 4 * 512;

#define STAGE_A(kt, buf)                                                      \
  {                                                                           \
    bf16_t* dstA = lds + (buf) * 32768 + ldsChunk;                            \
    const bf16_t* srcA = Ag + (kt) * 64;                                      \
    _Pragma("unroll")                                                         \
    for (int ci = 0; ci < 4; ++ci)                                            \
      async_copy16(srcA + (size_t)(ci * 8) * Kdim, dstA + ci * 512);          \
  }
#define STAGE_B(kt, buf)                                                      \
  {                                                                           \
    bf16_t* dstB = lds + (buf) * 32768 + 16384 + ldsChunk;                    \
    const bf16_t* srcB = Bg + (kt) * 64;                                      \
    _Pragma("unroll")                                                         \
    for (int ci = 0; ci < 4; ++ci)                                            \
      async_copy16(srcB + (size_t)(ci * 8) * Kdim, dstB + ci * 512);          \
  }

  f32x4 acc[8][4] = {};
  STAGE_A(0, 0); STAGE_B(0, 0); STAGE_A(1, 1); STAGE_B(1, 1);

  const int k0off = (quad * 8) ^ swz;
  const int k1off = (32 + quad * 8) ^ swz;

  for (int k = 0; k < nK; ++k) {
    const int cur = k & 1;
    const bf16_t* Asb = lds + cur * 32768;
    const bf16_t* Bsb = Asb + 16384;
    if (k < nK - 1) asm volatile("s_waitcnt vmcnt(8)" ::: "memory");
    else            asm volatile("s_waitcnt vmcnt(0)" ::: "memory");
    __builtin_amdgcn_s_barrier();
    __builtin_amdgcn_sched_barrier(0);

    bf16x8 a0[8], b0[4], a1[8], b1[4];
#pragma unroll
    for (int i = 0; i < 8; ++i)
      a0[i] = *(const bf16x8*)&Asb[(wm * 128 + i * 16 + l16) * 64 + k0off];
#pragma unroll
    for (int j = 0; j < 4; ++j)
      b0[j] = *(const bf16x8*)&Bsb[(wn * 64 + j * 16 + l16) * 64 + k0off];
    asm volatile("s_waitcnt lgkmcnt(0)" ::: "memory");
    __builtin_amdgcn_sched_barrier(0);
    __builtin_amdgcn_s_setprio(1);
#pragma unroll
    for (int i = 0; i < 4; ++i)
#pragma unroll
      for (int j = 0; j < 4; ++j)
        acc[i][j] = __builtin_amdgcn_mfma_f32_16x16x32_bf16(a0[i], b0[j], acc[i][j], 0, 0, 0);
    __builtin_amdgcn_s_setprio(0);

#pragma unroll
    for (int i = 0; i < 8; ++i)
      a1[i] = *(const bf16x8*)&Asb[(wm * 128 + i * 16 + l16) * 64 + k1off];
#pragma unroll
    for (int j = 0; j < 4; ++j)
      b1[j] = *(const bf16x8*)&Bsb[(wn * 64 + j * 16 + l16) * 64 + k1off];
    __builtin_amdgcn_s_setprio(1);
#pragma unroll
    for (int i = 4; i < 8; ++i)
#pragma unroll
      for (int j = 0; j < 4; ++j)
        acc[i][j] = __builtin_amdgcn_mfma_f32_16x16x32_bf16(a0[i], b0[j], acc[i][j], 0, 0, 0);
    __builtin_amdgcn_s_setprio(0);
    asm volatile("s_waitcnt lgkmcnt(0)" ::: "memory");
    __builtin_amdgcn_s_barrier();
    __builtin_amdgcn_sched_barrier(0);

    if (k + 2 < nK) STAGE_A(k + 2, cur);
    __builtin_amdgcn_s_setprio(1);
#pragma unroll
    for (int i = 0; i < 4; ++i)
#pragma unroll
      for (int j = 0; j < 4; ++j)
        acc[i][j] = __builtin_amdgcn_mfma_f32_16x16x32_bf16(a1[i], b1[j], acc[i][j], 0, 0, 0);
    __builtin_amdgcn_s_setprio(0);

    if (k + 2 < nK) STAGE_B(k + 2, cur);
    __builtin_amdgcn_s_setprio(1);
#pragma unroll
    for (int i = 4; i < 8; ++i)
#pragma unroll
      for (int j = 0; j < 4; ++j)
        acc[i][j] = __builtin_amdgcn_mfma_f32_16x16x32_bf16(a1[i], b1[j], acc[i][j], 0, 0, 0);
    __builtin_amdgcn_s_setprio(0);
  }
#undef STAGE_A
#undef STAGE_B

  // epilogue: LDS-staged tile + fused RoPE, coalesced stores
  {
    const int proj = n0 >> 11;
    bf16_t* dst = proj == 0 ? Qo : Ko;
    bf16_t* Ct = lds;
#pragma unroll
    for (int i = 0; i < 8; ++i)
#pragma unroll
      for (int j = 0; j < 4; ++j) {
        int coll = wn * 64 + j * 16 + l16;
        int pcol = coll + ((coll >> 7) << 2);
#pragma unroll
        for (int r = 0; r < 4; ++r) {
          int rowl = wm * 128 + i * 16 + quad * 4 + r;
          Ct[rowl * 268 + pcol] = (bf16_t)acc[i][j][r];
        }
      }
    __syncthreads();
    const int lane16 = tid & 15;
    const int slot0  = tid >> 4;
    const int d0 = lane16 * 8;
    const int dp = d0 ^ 64;
    const float sgn = (d0 < 64) ? -1.f : 1.f;
    const int b = m0 >> 11;
    const int hbase = (n0 & (CC - 1)) >> 7;
#pragma unroll
    for (int p = 0; p < 16; ++p) {
      int gslot = p * 32 + slot0;
      int rowl = gslot >> 1, hh = gslot & 1;
      int t = (m0 + rowl) & (TT - 1);
      const bf16_t* src = Ct + rowl * 268 + hh * 132;
      bf16x8 self = *(const bf16x8*)(src + d0);
      bf16x8 part = *(const bf16x8*)(src + dp);
      const float* ct = cosT + t * HD + d0;
      const float* st = sinT + t * HD + d0;
      float4 c0 = *(const float4*)(ct);
      float4 c1 = *(const float4*)(ct + 4);
      float4 s0 = *(const float4*)(st);
      float4 s1 = *(const float4*)(st + 4);
      float cc[8] = {c0.x, c0.y, c0.z, c0.w, c1.x, c1.y, c1.z, c1.w};
      float ss[8] = {s0.x, s0.y, s0.z, s0.w, s1.x, s1.y, s1.z, s1.w};
      bf16x8 o8;
#pragma unroll
      for (int e = 0; e < 8; ++e)
        o8[e] = (bf16_t)((float)self[e] * cc[e] + sgn * (float)part[e] * ss[e]);
      *(bf16x8*)(dst + (((size_t)(b * HH + hbase + hh) * TT + t) * HD) + d0) = o8;
    }
  }
}

// ---------------- 128x256 Wo GEMM, counted-vmcnt pipeline ------------------
// 256 blocks (32 m x 8 n) = one packed round. 8 waves (2M x 4N), per-wave
// 64x64, BK=64 double-buffered (96KB dynamic LDS). vmcnt(6).
__global__ __launch_bounds__(512, 2)
void gemm_wo(const bf16_t* __restrict__ A, const bf16_t* __restrict__ Bw,
             float* __restrict__ C, int Kdim) {
  extern __shared__ __align__(16) char smem[];
  bf16_t* lds = (bf16_t*)smem;   // buf b: A[128][64] at b*24576, B[256][64] at +8192
  const int tid  = threadIdx.x;
  const int wave = tid >> 6, lane = tid & 63;
  const int quad = lane >> 4, l16 = lane & 15;
  const int wm = wave >> 2, wn = wave & 3;
  const int n0 = blockIdx.x * 256, m0 = blockIdx.y * 128;

  const int srow = lane >> 3;
  const int scol = ((lane & 7) ^ srow) * 8;
  const int swz  = (l16 & 7) * 8;
  const int nK = Kdim >> 6;

#define WSTAGE_A(kt, buf)                                                     \
  {                                                                           \
    bf16_t* d_ = lds + (buf) * 24576;                                         \
    _Pragma("unroll")                                                         \
    for (int c_ = 0; c_ < 2; ++c_) {                                          \
      int ch_ = wave * 2 + c_;                                                \
      async_copy16(A + (size_t)(m0 + ch_ * 8 + srow) * Kdim + (kt) * 64 + scol,\
                   d_ + ch_ * 512);                                           \
    }                                                                         \
  }
#define WSTAGE_B(kt, buf)                                                     \
  {                                                                           \
    bf16_t* d_ = lds + (buf) * 24576 + 8192;                                  \
    _Pragma("unroll")                                                         \
    for (int c_ = 0; c_ < 4; ++c_) {                                          \
      int ch_ = wave * 4 + c_;                                                \
      async_copy16(Bw + (size_t)(n0 + ch_ * 8 + srow) * Kdim + (kt) * 64 + scol,\
                   d_ + ch_ * 512);                                           \
    }                                                                         \
  }

  f32x4 acc[4][4] = {};
  WSTAGE_A(0, 0); WSTAGE_B(0, 0); WSTAGE_A(1, 1); WSTAGE_B(1, 1);

  const int k0off = (quad * 8) ^ swz;
  const int k1off = (32 + quad * 8) ^ swz;

  for (int k = 0; k < nK; ++k) {
    const int cur = k & 1;
    const bf16_t* As = lds + cur * 24576;
    const bf16_t* Bs = As + 8192;
    if (k < nK - 1) asm volatile("s_waitcnt vmcnt(6)" ::: "memory");
    else            asm volatile("s_waitcnt vmcnt(0)" ::: "memory");
    __builtin_amdgcn_s_barrier();
    __builtin_amdgcn_sched_barrier(0);

    bf16x8 a0[4], b0[4], a1[4], b1[4];
#pragma unroll
    for (int i = 0; i < 4; ++i)
      a0[i] = *(const bf16x8*)&As[(wm * 64 + i * 16 + l16) * 64 + k0off];
#pragma unroll
    for (int j = 0; j < 4; ++j)
      b0[j] = *(const bf16x8*)&Bs[(wn * 64 + j * 16 + l16) * 64 + k0off];
    asm volatile("s_waitcnt lgkmcnt(0)" ::: "memory");
    __builtin_amdgcn_sched_barrier(0);
    __builtin_amdgcn_s_setprio(1);
#pragma unroll
    for (int i = 0; i < 4; ++i)
#pragma unroll
      for (int j = 0; j < 2; ++j)
        acc[i][j] = __builtin_amdgcn_mfma_f32_16x16x32_bf16(a0[i], b0[j], acc[i][j], 0, 0, 0);
    __builtin_amdgcn_s_setprio(0);

#pragma unroll
    for (int i = 0; i < 4; ++i)
      a1[i] = *(const bf16x8*)&As[(wm * 64 + i * 16 + l16) * 64 + k1off];
#pragma unroll
    for (int j = 0; j < 4; ++j)
      b1[j] = *(const bf16x8*)&Bs[(wn * 64 + j * 16 + l16) * 64 + k1off];
    __builtin_amdgcn_s_setprio(1);
#pragma unroll
    for (int i = 0; i < 4; ++i)
#pragma unroll
      for (int j = 2; j < 4; ++j)
        acc[i][j] = __builtin_amdgcn_mfma_f32_16x16x32_bf16(a0[i], b0[j], acc[i][j], 0, 0, 0);
    __builtin_amdgcn_s_setprio(0);
    asm volatile("s_waitcnt lgkmcnt(0)" ::: "memory");
    __builtin_amdgcn_s_barrier();
    __builtin_amdgcn_sched_barrier(0);

    if (k + 2 < nK) WSTAGE_A(k + 2, cur);
    __builtin_amdgcn_s_setprio(1);
#pragma unroll
    for (int i = 0; i < 4; ++i)
#pragma unroll
      for (int j = 0; j < 2; ++j)
        acc[i][j] = __builtin_amdgcn_mfma_f32_16x16x32_bf16(a1[i], b1[j], acc[i][j], 0, 0, 0);
    __builtin_amdgcn_s_setprio(0);

    if (k + 2 < nK) WSTAGE_B(k + 2, cur);
    __builtin_amdgcn_s_setprio(1);
#pragma unroll
    for (int i = 0; i < 4; ++i)
#pragma unroll
      for (int j = 2; j < 4; ++j)
        acc[i][j] = __builtin_amdgcn_mfma_f32_16x16x32_bf16(a1[i], b1[j], acc[i][j], 0, 0, 0);
    __builtin_amdgcn_s_setprio(0);
  }
#undef WSTAGE_A
#undef WSTAGE_B

#pragma unroll
  for (int i = 0; i < 4; ++i)
#pragma unroll
    for (int j = 0; j < 4; ++j) {
      int gcol = n0 + wn * 64 + j * 16 + l16;
#pragma unroll
      for (int r = 0; r < 4; ++r) {
        int grow = m0 + wm * 64 + i * 16 + quad * 4 + r;
        C[(size_t)grow * CC + gcol] = acc[i][j][r];
      }
    }
}

// ---------------- flash attention (causal), 4 waves, 2 blocks/CU ----------
// 512 blocks, 256 threads. LDS trimmed to 72KB (Ks 32 + Vs 32 + Pl 8) so two
// blocks co-reside per CU with slack (round-8's exact-fit 2x80KB=160KB failed:
// OccupancyPercent 13.4 = one block resident). Pl is ONE per-wave buffer
// time-shared across the two m-tiles: write P(mt0) -> read pf[0] -> write
// P(mt1) -> read pf[1]. DS ops from a wave process in issue order, so the
// cross-lane WAR (mt1 writes over slots just read for pf[0]) is safe;
// sched_barrier(0) pins compile-time order.
__global__ __launch_bounds__(256, 2)
void attn_kernel(const bf16_t* __restrict__ Q, const bf16_t* __restrict__ K,
                 const bf16_t* __restrict__ Vt, bf16_t* __restrict__ Out) {
  __shared__ __align__(16) bf16_t Ks[2][64 * 128];   // 32KB, swizzled
  __shared__ __align__(16) bf16_t Vs[2][128 * 64];   // 32KB, swizzled
  __shared__ __align__(16) bf16_t Pl[4][16 * 64];    // 8KB, XOR-swizzled, mt-shared
  const int lane = threadIdx.x & 63, wave = threadIdx.x >> 6;
  const int quad = lane >> 4, l16 = lane & 15;
  const int linear = blockIdx.x;
  const int hb = linear & 31;
  const int h = hb & (HH - 1), b = hb >> 4;
  const int qt = (TT / 128 - 1) - (linear >> 5);  // reversed: big qt first
  const int q0 = qt * 128 + wave * 32;            // m-tile A rows; B at +16
  const size_t qkbase = (size_t)(b * HH + h) * TT * HD;
  const bf16_t* Kh = K + qkbase;
  const bf16_t* Vh = Vt + (size_t)(b * HH + h) * HD * TT;
  const float scale = 0.08838834764831845f;  // hd^-0.5

  // staging address components (wave moves 4 K-chunks + 4 V-chunks)
  const int srK = lane >> 4;
  const int sgK = lane & 15;
  const int scK0 = (sgK ^ srK) * 8;         // even chunk (r&7 = srK)
  const int scK1 = (sgK ^ (4 + srK)) * 8;   // odd chunk  (r&7 = 4+srK)
  const int srV = lane >> 3;
  const int scV = (((lane & 7) ^ srV) & 7) * 8;
  const int swz = (l16 & 7) * 8;
  const int psw = (l16 & 7) << 3;           // P read-side xor (elements)

  // Q A-fragments for both m-tiles
  bf16x8 qf[2][4];
#pragma unroll
  for (int mt = 0; mt < 2; ++mt) {
    const bf16_t* qrow = Q + qkbase + (size_t)(q0 + mt * 16 + l16) * HD;
#pragma unroll
    for (int kc = 0; kc < 4; ++kc) qf[mt][kc] = *(const bf16x8*)(qrow + kc * 32 + quad * 8);
  }

  f32x4 o[2][8] = {};
  float l_i[2][4] = {};

  const int nIter = qt * 2 + 2;   // even

  // initial prefetch into buffer 0
  {
#pragma unroll
    for (int i = 0; i < 4; ++i) {
      int chunk = wave * 4 + i;
      int sc = (chunk & 1) ? scK1 : scK0;
      async_copy16(Kh + (size_t)(chunk * 4 + srK) * HD + sc, &Ks[0][chunk * 512]);
    }
#pragma unroll
    for (int i = 0; i < 4; ++i) {
      int chunk = wave * 4 + i;
      async_copy16(Vh + (size_t)(chunk * 8 + srV) * TT + scV, &Vs[0][chunk * 512]);
    }
  }

  for (int it = 0; it < nIter; ++it) {
    const int cur = it & 1;
    const int key0 = it * 64;
    __syncthreads();   // drains copies into buf cur; orders prev compute reads

    if (it + 1 < nIter) {
      const int nxt = cur ^ 1;
      const int knxt = key0 + 64;
#pragma unroll
      for (int i = 0; i < 4; ++i) {
        int chunk = wave * 4 + i;
        int sc = (chunk & 1) ? scK1 : scK0;
        async_copy16(Kh + (size_t)(knxt + chunk * 4 + srK) * HD + sc, &Ks[nxt][chunk * 512]);
      }
#pragma unroll
      for (int i = 0; i < 4; ++i) {
        int chunk = wave * 4 + i;
        async_copy16(Vh + (size_t)(chunk * 8 + srV) * TT + knxt + scV, &Vs[nxt][chunk * 512]);
      }
    }

    // S = Q K^T, both m-tiles share K-fragments
    f32x4 s[2][4] = {};
#pragma unroll
    for (int kc = 0; kc < 4; ++kc) {
      const int koff = (kc * 32 + quad * 8) ^ swz;
#pragma unroll
      for (int kt = 0; kt < 4; ++kt) {
        bf16x8 kf = *(const bf16x8*)&Ks[cur][(kt * 16 + l16) * 128 + koff];
        s[0][kt] = __builtin_amdgcn_mfma_f32_16x16x32_bf16(qf[0][kc], kf, s[0][kt], 0, 0, 0);
        s[1][kt] = __builtin_amdgcn_mfma_f32_16x16x32_bf16(qf[1][kc], kf, s[1][kt], 0, 0, 0);
      }
    }

    // exp+mask -> P -> LDS -> fragments, one m-tile at a time (shared buffer)
    bf16_t* pl = &Pl[wave][0];
    bf16x8 pf[2][2];
#pragma unroll
    for (int mt = 0; mt < 2; ++mt) {
#pragma unroll
      for (int r = 0; r < 4; ++r) {
        int prow = quad * 4 + r;
        int rel = q0 + mt * 16 + prow - key0;  // cols <= rel survive
        int rbase = prow * 64;
        int sw = (prow & 7) << 3;
        float lr = 0.f;
#pragma unroll
        for (int kt = 0; kt < 4; ++kt) {
          int c16 = kt * 16 + l16;
          float e = (c16 > rel) ? 0.f : __expf(s[mt][kt][r] * scale);
          lr += e;
          pl[rbase + (c16 ^ sw)] = (bf16_t)e;
        }
        l_i[mt][r] += lr;
      }
      pf[mt][0] = *(const bf16x8*)&pl[l16 * 64 + ((quad * 8) ^ psw)];
      pf[mt][1] = *(const bf16x8*)&pl[l16 * 64 + ((32 + quad * 8) ^ psw)];
      __builtin_amdgcn_sched_barrier(0);   // pin order: reads before mt1 writes
    }

    // PV: V-fragments shared by both m-tiles
    const int voff0 = (quad * 8) ^ swz;
    const int voff1 = (32 + quad * 8) ^ swz;
#pragma unroll
    for (int n = 0; n < 8; ++n) {
      bf16x8 vf0 = *(const bf16x8*)&Vs[cur][(n * 16 + l16) * 64 + voff0];
      bf16x8 vf1 = *(const bf16x8*)&Vs[cur][(n * 16 + l16) * 64 + voff1];
      o[0][n] = __builtin_amdgcn_mfma_f32_16x16x32_bf16(pf[0][0], vf0, o[0][n], 0, 0, 0);
      o[0][n] = __builtin_amdgcn_mfma_f32_16x16x32_bf16(pf[0][1], vf1, o[0][n], 0, 0, 0);
      o[1][n] = __builtin_amdgcn_mfma_f32_16x16x32_bf16(pf[1][0], vf0, o[1][n], 0, 0, 0);
      o[1][n] = __builtin_amdgcn_mfma_f32_16x16x32_bf16(pf[1][1], vf1, o[1][n], 0, 0, 0);
    }
  }

  // reduce l across the 16-lane row group (one butterfly, once)
#pragma unroll
  for (int mt = 0; mt < 2; ++mt)
#pragma unroll
    for (int r = 0; r < 4; ++r) {
      float l = l_i[mt][r];
#pragma unroll
      for (int off = 1; off < 16; off <<= 1) l += __shfl_xor(l, off);
      l_i[mt][r] = 1.f / l;
    }

#pragma unroll
  for (int mt = 0; mt < 2; ++mt)
#pragma unroll
    for (int n = 0; n < 8; ++n)
#pragma unroll
      for (int r = 0; r < 4; ++r) {
        int qg = q0 + mt * 16 + quad * 4 + r;
        size_t off = ((size_t)(b * TT + qg) * CC) + h * HD + n * 16 + l16;
        Out[off] = (bf16_t)(o[mt][n][r] * l_i[mt][r]);
      }
}

extern "C" void kernel_launch(void* const* d_in, const int* in_sizes, int n_in,
                              void* d_out, int out_size, void* d_ws, size_t ws_size,
                              hipStream_t stream) {
  const float* x    = (const float*)d_in[0];
  const float* cosT = (const float*)d_in[1];
  const float* sinT = (const float*)d_in[2];
  // d_in[3] = mask (unused; causal pattern is hard-coded)
  const float* Wq = (const float*)d_in[4];
  const float* Wk = (const float*)d_in[5];
  const float* Wv = (const float*)d_in[6];
  const float* Wo = (const float*)d_in[7];
  float* out = (float*)d_out;

  char* ws = (char*)d_ws;
  const size_t XSZ = (size_t)BB * TT * CC * 2;  // 16 MB (bf16)
  const size_t WSZ = (size_t)CC * CC * 2;       // 8 MB (bf16)
  bf16_t* x_bf  = (bf16_t*)(ws);
  bf16_t* wq_bf = (bf16_t*)(ws + XSZ);          // wq/wk/wv/wo contiguous
  bf16_t* wv_bf = (bf16_t*)(ws + XSZ + 2 * WSZ);
  bf16_t* wo_bf = (bf16_t*)(ws + XSZ + 3 * WSZ);
  bf16_t* Qb    = (bf16_t*)(ws + XSZ + 4 * WSZ);
  bf16_t* Kb    = (bf16_t*)(ws + 2 * XSZ + 4 * WSZ);
  bf16_t* Vt    = (bf16_t*)(ws + 3 * XSZ + 4 * WSZ);
  bf16_t* attn_bf = x_bf;  // x_bf dead after projections; alias saves 16 MB

  const int NX = BB * TT * CC;  // 8388608
  const int NW = CC * CC;       // 4194304
  cast_all<<<(NX / 4 + 4 * (NW / 4)) / 256, 256, 0, stream>>>(
      x, Wq, Wk, Wv, Wo, x_bf, wq_bf);

  // Q+K projection + fused RoPE: 256 blocks = one perfectly packed round
  (void)hipFuncSetAttribute(reinterpret_cast<const void*>(gemm_qkv256),
                            hipFuncAttributeMaxDynamicSharedMemorySize, 137216);
  gemm_qkv256<<<dim3(2 * CC / 256, BB * TT / 256), 512, 137216, stream>>>(
      x_bf, wq_bf, Qb, Kb, cosT, sinT, CC);

  // V projection: 128^2 tiles, 512 blocks (2+ blocks/CU, well balanced)
  gemm_v<<<dim3(CC / 128, BB * TT / 128), 256, 0, stream>>>(
      x_bf, wv_bf, Vt, CC);

  // attention: 512 blocks x 256 threads, 72KB LDS -> 2 blocks/CU (with slack)
  attn_kernel<<<dim3(BB * HH * (TT / 128)), 256, 0, stream>>>(Qb, Kb, Vt, attn_bf);

  // Wo projection: 128x256 tiles, 256 blocks = one packed round
  (void)hipFuncSetAttribute(reinterpret_cast<const void*>(gemm_wo),
                            hipFuncAttributeMaxDynamicSharedMemorySize, 98304);
  gemm_wo<<<dim3(CC / 256, BB * TT / 128), 512, 98304, stream>>>(
      attn_bf, wo_bf, out, CC);
}

// Round 10
// 351.894 us; speedup vs baseline: 1.0432x; 1.0432x over previous
//
#include <hip/hip_runtime.h>
#include <cstdint>

typedef __bf16 bf16_t;
typedef __bf16 bf16x8 __attribute__((ext_vector_type(8)));
typedef __bf16 bf16x4 __attribute__((ext_vector_type(4)));
typedef float  f32x4  __attribute__((ext_vector_type(4)));

// Problem constants (B=2, T=2048, C=2048, H=16, hd=128)
#define BB 2
#define TT 2048
#define CC 2048
#define HH 16
#define HD 128

static __device__ __forceinline__ void async_copy16(const void* gp, void* lp) {
  __builtin_amdgcn_global_load_lds(
      (const __attribute__((address_space(1))) void*)(uintptr_t)gp,
      (__attribute__((address_space(3))) void*)(uint32_t)(uintptr_t)lp,
      16, 0, 0);
}

// ---------------- fused cast f32 -> bf16 for x + 4 weights ----------------
__global__ __launch_bounds__(256)
void cast_all(const float* __restrict__ x, const float* __restrict__ wq,
              const float* __restrict__ wk, const float* __restrict__ wv,
              const float* __restrict__ wo, bf16_t* __restrict__ xb,
              bf16_t* __restrict__ wq_b) {
  const int NX4 = (BB * TT * CC) / 4;  // 2097152
  const int NW4 = (CC * CC) / 4;       // 1048576
  int i = blockIdx.x * 256 + threadIdx.x;
  const float* s;
  bf16_t* d;
  int off;
  if (i < NX4) {
    s = x; d = xb; off = i;
  } else {
    int j = i - NX4;
    int w = j >> 20;            // NW4 = 2^20
    off = j & (NW4 - 1);
    s = (w == 0) ? wq : (w == 1) ? wk : (w == 2) ? wv : wo;
    d = wq_b + (size_t)w * (CC * CC);
  }
  float4 v = ((const float4*)s)[off];
  bf16x4 o;
  o[0] = (bf16_t)v.x; o[1] = (bf16_t)v.y; o[2] = (bf16_t)v.z; o[3] = (bf16_t)v.w;
  ((bf16x4*)d)[off] = o;
}

// ---------------- 128x128 GEMM: V projection -> V^T [B,H,hd,T] -------------
__global__ __launch_bounds__(256)
void gemm_v(const bf16_t* __restrict__ A, const bf16_t* __restrict__ Bw,
            bf16_t* __restrict__ C2, int Kdim) {
  __shared__ __align__(16) char smem[128 * 136 * 2];  // As+Bs (32KB) / Ct (34KB)
  bf16_t* As = (bf16_t*)smem;
  bf16_t* Bs = (bf16_t*)(smem + 16384);
  const int tid  = threadIdx.x;
  const int wave = tid >> 6, lane = tid & 63;
  const int quad = lane >> 4, l16 = lane & 15;
  const int m0 = blockIdx.y * 128, n0 = blockIdx.x * 128;
  const int wm = (wave >> 1) * 64, wn = (wave & 1) * 64;

  f32x4 acc[4][4] = {};

  const int srow = lane >> 3;                       // row in 8-row chunk (=r&7)
  const int scol = (((lane & 7) ^ srow) & 7) * 8;   // swizzled source col
  const int swz  = (l16 & 7) * 8;                   // read-side xor (elements)

  for (int k0 = 0; k0 < Kdim; k0 += 64) {
#pragma unroll
    for (int i = 0; i < 4; ++i) {
      int chunk = wave * 4 + i;
      int row = chunk * 8 + srow;
      async_copy16(A + (size_t)(m0 + row) * Kdim + k0 + scol, As + chunk * 512);
    }
#pragma unroll
    for (int i = 0; i < 4; ++i) {
      int chunk = wave * 4 + i;
      int row = chunk * 8 + srow;
      async_copy16(Bw + (size_t)(n0 + row) * Kdim + k0 + scol, Bs + chunk * 512);
    }
    __syncthreads();
#pragma unroll
    for (int kk = 0; kk < 64; kk += 32) {
      const int koff = (kk + quad * 8) ^ swz;
      bf16x8 af[4], bfr[4];
#pragma unroll
      for (int i = 0; i < 4; ++i)
        af[i] = *(const bf16x8*)&As[(wm + i * 16 + l16) * 64 + koff];
#pragma unroll
      for (int j = 0; j < 4; ++j)
        bfr[j] = *(const bf16x8*)&Bs[(wn + j * 16 + l16) * 64 + koff];
#pragma unroll
      for (int i = 0; i < 4; ++i)
#pragma unroll
        for (int j = 0; j < 4; ++j)
          acc[i][j] = __builtin_amdgcn_mfma_f32_16x16x32_bf16(af[i], bfr[j], acc[i][j], 0, 0, 0);
    }
    __syncthreads();
  }

  // V: stage tile in LDS (stride 136), then coalesced writes along T
  const int h = (n0 & (CC - 1)) >> 7;
  bf16_t* Ct = (bf16_t*)smem;
  __syncthreads();
#pragma unroll
  for (int i = 0; i < 4; ++i)
#pragma unroll
    for (int j = 0; j < 4; ++j) {
      int c = wn + j * 16 + l16;
#pragma unroll
      for (int r = 0; r < 4; ++r)
        Ct[(wm + i * 16 + quad * 4 + r) * 136 + c] = (bf16_t)acc[i][j][r];
    }
  __syncthreads();
  const unsigned short* Cu = (const unsigned short*)Ct;
  int col = tid >> 1;                 // d within head: 0..127
  int rh  = (tid & 1) * 64;           // row half
  int grow0 = m0 + rh;
  int b = grow0 >> 11, t0 = grow0 & (TT - 1);
  unsigned int pk[32];
#pragma unroll
  for (int s = 0; s < 32; ++s) {
    unsigned int lo = Cu[(rh + 2 * s) * 136 + col];
    unsigned int hi = Cu[(rh + 2 * s + 1) * 136 + col];
    pk[s] = lo | (hi << 16);
  }
  bf16_t* dstp = C2 + ((size_t)(b * HH + h) * HD + col) * TT + t0;
#pragma unroll
  for (int u = 0; u < 8; ++u) {
    uint4 w; w.x = pk[4*u]; w.y = pk[4*u+1]; w.z = pk[4*u+2]; w.w = pk[4*u+3];
    *(uint4*)(dstp + 8 * u) = w;
  }
}

// ---------------- 256x256 fused QK GEMM + fused RoPE epilogue --------------
// (round-6, verified: WRITE_SIZE 32.8MB, ~71us, 968 TF)
__global__ __launch_bounds__(512, 2)
void gemm_qkv256(const bf16_t* __restrict__ A, const bf16_t* __restrict__ Bw,
                 bf16_t* __restrict__ Qo, bf16_t* __restrict__ Ko,
                 const float* __restrict__ cosT, const float* __restrict__ sinT,
                 int Kdim) {
  extern __shared__ __align__(16) char smem[];
  bf16_t* lds = (bf16_t*)smem;
  const int tid  = threadIdx.x;
  const int wave = tid >> 6, lane = tid & 63;
  const int quad = lane >> 4, l16 = lane & 15;
  const int wm = wave >> 2, wn = wave & 3;
  const int n0 = blockIdx.x * 256, m0 = blockIdx.y * 256;

  const int srow = lane >> 3;
  const int scol = ((lane & 7) ^ srow) * 8;
  const int swz  = (l16 & 7) * 8;
  const int nK = Kdim >> 6;

  const bf16_t* Ag = A  + (size_t)(m0 + wave * 32 + srow) * Kdim + scol;
  const bf16_t* Bg = Bw + (size_t)(n0 + wave * 32 + srow) * Kdim + scol;
  const int ldsChunk = wave * 4 * 512;

#define STAGE_A(kt, buf)                                                      \
  {                                                                           \
    bf16_t* dstA = lds + (buf) * 32768 + ldsChunk;                            \
    const bf16_t* srcA = Ag + (kt) * 64;                                      \
    _Pragma("unroll")                                                         \
    for (int ci = 0; ci < 4; ++ci)                                            \
      async_copy16(srcA + (size_t)(ci * 8) * Kdim, dstA + ci * 512);          \
  }
#define STAGE_B(kt, buf)                                                      \
  {                                                                           \
    bf16_t* dstB = lds + (buf) * 32768 + 16384 + ldsChunk;                    \
    const bf16_t* srcB = Bg + (kt) * 64;                                      \
    _Pragma("unroll")                                                         \
    for (int ci = 0; ci < 4; ++ci)                                            \
      async_copy16(srcB + (size_t)(ci * 8) * Kdim, dstB + ci * 512);          \
  }

  f32x4 acc[8][4] = {};
  STAGE_A(0, 0); STAGE_B(0, 0); STAGE_A(1, 1); STAGE_B(1, 1);

  const int k0off = (quad * 8) ^ swz;
  const int k1off = (32 + quad * 8) ^ swz;

  for (int k = 0; k < nK; ++k) {
    const int cur = k & 1;
    const bf16_t* Asb = lds + cur * 32768;
    const bf16_t* Bsb = Asb + 16384;
    if (k < nK - 1) asm volatile("s_waitcnt vmcnt(8)" ::: "memory");
    else            asm volatile("s_waitcnt vmcnt(0)" ::: "memory");
    __builtin_amdgcn_s_barrier();
    __builtin_amdgcn_sched_barrier(0);

    bf16x8 a0[8], b0[4], a1[8], b1[4];
#pragma unroll
    for (int i = 0; i < 8; ++i)
      a0[i] = *(const bf16x8*)&Asb[(wm * 128 + i * 16 + l16) * 64 + k0off];
#pragma unroll
    for (int j = 0; j < 4; ++j)
      b0[j] = *(const bf16x8*)&Bsb[(wn * 64 + j * 16 + l16) * 64 + k0off];
    asm volatile("s_waitcnt lgkmcnt(0)" ::: "memory");
    __builtin_amdgcn_sched_barrier(0);
    __builtin_amdgcn_s_setprio(1);
#pragma unroll
    for (int i = 0; i < 4; ++i)
#pragma unroll
      for (int j = 0; j < 4; ++j)
        acc[i][j] = __builtin_amdgcn_mfma_f32_16x16x32_bf16(a0[i], b0[j], acc[i][j], 0, 0, 0);
    __builtin_amdgcn_s_setprio(0);

#pragma unroll
    for (int i = 0; i < 8; ++i)
      a1[i] = *(const bf16x8*)&Asb[(wm * 128 + i * 16 + l16) * 64 + k1off];
#pragma unroll
    for (int j = 0; j < 4; ++j)
      b1[j] = *(const bf16x8*)&Bsb[(wn * 64 + j * 16 + l16) * 64 + k1off];
    __builtin_amdgcn_s_setprio(1);
#pragma unroll
    for (int i = 4; i < 8; ++i)
#pragma unroll
      for (int j = 0; j < 4; ++j)
        acc[i][j] = __builtin_amdgcn_mfma_f32_16x16x32_bf16(a0[i], b0[j], acc[i][j], 0, 0, 0);
    __builtin_amdgcn_s_setprio(0);
    asm volatile("s_waitcnt lgkmcnt(0)" ::: "memory");
    __builtin_amdgcn_s_barrier();
    __builtin_amdgcn_sched_barrier(0);

    if (k + 2 < nK) STAGE_A(k + 2, cur);
    __builtin_amdgcn_s_setprio(1);
#pragma unroll
    for (int i = 0; i < 4; ++i)
#pragma unroll
      for (int j = 0; j < 4; ++j)
        acc[i][j] = __builtin_amdgcn_mfma_f32_16x16x32_bf16(a1[i], b1[j], acc[i][j], 0, 0, 0);
    __builtin_amdgcn_s_setprio(0);

    if (k + 2 < nK) STAGE_B(k + 2, cur);
    __builtin_amdgcn_s_setprio(1);
#pragma unroll
    for (int i = 4; i < 8; ++i)
#pragma unroll
      for (int j = 0; j < 4; ++j)
        acc[i][j] = __builtin_amdgcn_mfma_f32_16x16x32_bf16(a1[i], b1[j], acc[i][j], 0, 0, 0);
    __builtin_amdgcn_s_setprio(0);
  }
#undef STAGE_A
#undef STAGE_B

  // epilogue: LDS-staged tile + fused RoPE, coalesced stores
  {
    const int proj = n0 >> 11;
    bf16_t* dst = proj == 0 ? Qo : Ko;
    bf16_t* Ct = lds;
#pragma unroll
    for (int i = 0; i < 8; ++i)
#pragma unroll
      for (int j = 0; j < 4; ++j) {
        int coll = wn * 64 + j * 16 + l16;
        int pcol = coll + ((coll >> 7) << 2);
#pragma unroll
        for (int r = 0; r < 4; ++r) {
          int rowl = wm * 128 + i * 16 + quad * 4 + r;
          Ct[rowl * 268 + pcol] = (bf16_t)acc[i][j][r];
        }
      }
    __syncthreads();
    const int lane16 = tid & 15;
    const int slot0  = tid >> 4;
    const int d0 = lane16 * 8;
    const int dp = d0 ^ 64;
    const float sgn = (d0 < 64) ? -1.f : 1.f;
    const int b = m0 >> 11;
    const int hbase = (n0 & (CC - 1)) >> 7;
#pragma unroll
    for (int p = 0; p < 16; ++p) {
      int gslot = p * 32 + slot0;
      int rowl = gslot >> 1, hh = gslot & 1;
      int t = (m0 + rowl) & (TT - 1);
      const bf16_t* src = Ct + rowl * 268 + hh * 132;
      bf16x8 self = *(const bf16x8*)(src + d0);
      bf16x8 part = *(const bf16x8*)(src + dp);
      const float* ct = cosT + t * HD + d0;
      const float* st = sinT + t * HD + d0;
      float4 c0 = *(const float4*)(ct);
      float4 c1 = *(const float4*)(ct + 4);
      float4 s0 = *(const float4*)(st);
      float4 s1 = *(const float4*)(st + 4);
      float cc[8] = {c0.x, c0.y, c0.z, c0.w, c1.x, c1.y, c1.z, c1.w};
      float ss[8] = {s0.x, s0.y, s0.z, s0.w, s1.x, s1.y, s1.z, s1.w};
      bf16x8 o8;
#pragma unroll
      for (int e = 0; e < 8; ++e)
        o8[e] = (bf16_t)((float)self[e] * cc[e] + sgn * (float)part[e] * ss[e]);
      *(bf16x8*)(dst + (((size_t)(b * HH + hbase + hh) * TT + t) * HD) + d0) = o8;
    }
  }
}

// ---------------- 128x256 Wo GEMM, counted-vmcnt pipeline ------------------
// 256 blocks (32 m x 8 n) = one packed round. 8 waves (2M x 4N), per-wave
// 64x64, BK=64 double-buffered (96KB dynamic LDS). vmcnt(6).
__global__ __launch_bounds__(512, 2)
void gemm_wo(const bf16_t* __restrict__ A, const bf16_t* __restrict__ Bw,
             float* __restrict__ C, int Kdim) {
  extern __shared__ __align__(16) char smem[];
  bf16_t* lds = (bf16_t*)smem;   // buf b: A[128][64] at b*24576, B[256][64] at +8192
  const int tid  = threadIdx.x;
  const int wave = tid >> 6, lane = tid & 63;
  const int quad = lane >> 4, l16 = lane & 15;
  const int wm = wave >> 2, wn = wave & 3;
  const int n0 = blockIdx.x * 256, m0 = blockIdx.y * 128;

  const int srow = lane >> 3;
  const int scol = ((lane & 7) ^ srow) * 8;
  const int swz  = (l16 & 7) * 8;
  const int nK = Kdim >> 6;

#define WSTAGE_A(kt, buf)                                                     \
  {                                                                           \
    bf16_t* d_ = lds + (buf) * 24576;                                         \
    _Pragma("unroll")                                                         \
    for (int c_ = 0; c_ < 2; ++c_) {                                          \
      int ch_ = wave * 2 + c_;                                                \
      async_copy16(A + (size_t)(m0 + ch_ * 8 + srow) * Kdim + (kt) * 64 + scol,\
                   d_ + ch_ * 512);                                           \
    }                                                                         \
  }
#define WSTAGE_B(kt, buf)                                                     \
  {                                                                           \
    bf16_t* d_ = lds + (buf) * 24576 + 8192;                                  \
    _Pragma("unroll")                                                         \
    for (int c_ = 0; c_ < 4; ++c_) {                                          \
      int ch_ = wave * 4 + c_;                                                \
      async_copy16(Bw + (size_t)(n0 + ch_ * 8 + srow) * Kdim + (kt) * 64 + scol,\
                   d_ + ch_ * 512);                                           \
    }                                                                         \
  }

  f32x4 acc[4][4] = {};
  WSTAGE_A(0, 0); WSTAGE_B(0, 0); WSTAGE_A(1, 1); WSTAGE_B(1, 1);

  const int k0off = (quad * 8) ^ swz;
  const int k1off = (32 + quad * 8) ^ swz;

  for (int k = 0; k < nK; ++k) {
    const int cur = k & 1;
    const bf16_t* As = lds + cur * 24576;
    const bf16_t* Bs = As + 8192;
    if (k < nK - 1) asm volatile("s_waitcnt vmcnt(6)" ::: "memory");
    else            asm volatile("s_waitcnt vmcnt(0)" ::: "memory");
    __builtin_amdgcn_s_barrier();
    __builtin_amdgcn_sched_barrier(0);

    bf16x8 a0[4], b0[4], a1[4], b1[4];
#pragma unroll
    for (int i = 0; i < 4; ++i)
      a0[i] = *(const bf16x8*)&As[(wm * 64 + i * 16 + l16) * 64 + k0off];
#pragma unroll
    for (int j = 0; j < 4; ++j)
      b0[j] = *(const bf16x8*)&Bs[(wn * 64 + j * 16 + l16) * 64 + k0off];
    asm volatile("s_waitcnt lgkmcnt(0)" ::: "memory");
    __builtin_amdgcn_sched_barrier(0);
    __builtin_amdgcn_s_setprio(1);
#pragma unroll
    for (int i = 0; i < 4; ++i)
#pragma unroll
      for (int j = 0; j < 2; ++j)
        acc[i][j] = __builtin_amdgcn_mfma_f32_16x16x32_bf16(a0[i], b0[j], acc[i][j], 0, 0, 0);
    __builtin_amdgcn_s_setprio(0);

#pragma unroll
    for (int i = 0; i < 4; ++i)
      a1[i] = *(const bf16x8*)&As[(wm * 64 + i * 16 + l16) * 64 + k1off];
#pragma unroll
    for (int j = 0; j < 4; ++j)
      b1[j] = *(const bf16x8*)&Bs[(wn * 64 + j * 16 + l16) * 64 + k1off];
    __builtin_amdgcn_s_setprio(1);
#pragma unroll
    for (int i = 0; i < 4; ++i)
#pragma unroll
      for (int j = 2; j < 4; ++j)
        acc[i][j] = __builtin_amdgcn_mfma_f32_16x16x32_bf16(a0[i], b0[j], acc[i][j], 0, 0, 0);
    __builtin_amdgcn_s_setprio(0);
    asm volatile("s_waitcnt lgkmcnt(0)" ::: "memory");
    __builtin_amdgcn_s_barrier();
    __builtin_amdgcn_sched_barrier(0);

    if (k + 2 < nK) WSTAGE_A(k + 2, cur);
    __builtin_amdgcn_s_setprio(1);
#pragma unroll
    for (int i = 0; i < 4; ++i)
#pragma unroll
      for (int j = 0; j < 2; ++j)
        acc[i][j] = __builtin_amdgcn_mfma_f32_16x16x32_bf16(a1[i], b1[j], acc[i][j], 0, 0, 0);
    __builtin_amdgcn_s_setprio(0);

    if (k + 2 < nK) WSTAGE_B(k + 2, cur);
    __builtin_amdgcn_s_setprio(1);
#pragma unroll
    for (int i = 0; i < 4; ++i)
#pragma unroll
      for (int j = 2; j < 4; ++j)
        acc[i][j] = __builtin_amdgcn_mfma_f32_16x16x32_bf16(a1[i], b1[j], acc[i][j], 0, 0, 0);
    __builtin_amdgcn_s_setprio(0);
  }
#undef WSTAGE_A
#undef WSTAGE_B

#pragma unroll
  for (int i = 0; i < 4; ++i)
#pragma unroll
    for (int j = 0; j < 4; ++j) {
      int gcol = n0 + wn * 64 + j * 16 + l16;
#pragma unroll
      for (int r = 0; r < 4; ++r) {
        int grow = m0 + wm * 64 + i * 16 + quad * 4 + r;
        C[(size_t)grow * CC + gcol] = acc[i][j][r];
      }
    }
}

// ---------------- flash attention (causal), 8 waves, balanced grid ---------
// Round-6 structure (fastest measured: 67.6us) + r9-verified Pl fix.
// 256 blocks (one per CU, single round). Block = (b,h,spair): processes TWO
// 128-row q-tiles, qt = 15-spair then qt = spair -> every block runs exactly
// 34 key-iterations (perfect balance). 8 waves x 16 q-rows each.
// Pl: stride 64 + XOR swizzle (elem ^= (row&7)<<3, verified r9): removes the
// 4-way conflict measured at 5.0M cycles on the stride-72/76 variants.
__global__ __launch_bounds__(512, 2)
void attn_kernel(const bf16_t* __restrict__ Q, const bf16_t* __restrict__ K,
                 const bf16_t* __restrict__ Vt, bf16_t* __restrict__ Out) {
  __shared__ __align__(16) bf16_t Ks[2][64 * 128];   // 32KB, swizzled
  __shared__ __align__(16) bf16_t Vs[2][128 * 64];   // 32KB, swizzled
  __shared__ __align__(16) bf16_t Pl[8][16 * 64];    // 16KB, XOR-swizzled
  const int lane = threadIdx.x & 63, wave = threadIdx.x >> 6;
  const int quad = lane >> 4, l16 = lane & 15;
  const int linear = blockIdx.x;           // 0..255
  const int hb = linear & 31;
  const int h = hb & (HH - 1), b = hb >> 4;
  const int spair = linear >> 5;           // 0..7
  const size_t qkbase = (size_t)(b * HH + h) * TT * HD;
  const bf16_t* Kh = K + qkbase;
  const bf16_t* Vh = Vt + (size_t)(b * HH + h) * HD * TT;
  const float scale = 0.08838834764831845f;  // hd^-0.5

  // staging address components (wave moves 2 K-chunks + 2 V-chunks)
  const int srK = lane >> 4;
  const int sgK = lane & 15;
  const int scK0 = (sgK ^ srK) * 8;         // even chunk (r&7 = srK)
  const int scK1 = (sgK ^ (4 + srK)) * 8;   // odd chunk  (r&7 = 4+srK)
  const int srV = lane >> 3;
  const int scV = (((lane & 7) ^ srV) & 7) * 8;
  const int swz = (l16 & 7) * 8;
  const int psw = (l16 & 7) << 3;           // P read-side xor (elements)

#pragma unroll
  for (int half = 0; half < 2; ++half) {
    const int qt = half == 0 ? (15 - spair) : spair;
    const int q0 = qt * 128 + wave * 16;    // this wave's 16 q-rows
    const int nIter = qt * 2 + 2;           // even

    // Q A-fragments: A[m=l16][k=quad*8+j] (direct from global)
    bf16x8 qf[4];
    {
      const bf16_t* qrow = Q + qkbase + (size_t)(q0 + l16) * HD;
#pragma unroll
      for (int kc = 0; kc < 4; ++kc) qf[kc] = *(const bf16x8*)(qrow + kc * 32 + quad * 8);
    }

    f32x4 o[8] = {};
    float l_i[4] = {};

    // initial prefetch into buffer 0 (prev tile's last reads were buf1)
    {
#pragma unroll
      for (int i = 0; i < 2; ++i) {
        int chunk = wave * 2 + i;
        int sc = (chunk & 1) ? scK1 : scK0;
        async_copy16(Kh + (size_t)(chunk * 4 + srK) * HD + sc, &Ks[0][chunk * 512]);
      }
#pragma unroll
      for (int i = 0; i < 2; ++i) {
        int chunk = wave * 2 + i;
        async_copy16(Vh + (size_t)(chunk * 8 + srV) * TT + scV, &Vs[0][chunk * 512]);
      }
    }

    for (int it = 0; it < nIter; ++it) {
      const int cur = it & 1;
      const int key0 = it * 64;
      __syncthreads();   // drains copies into buf cur; orders prev compute reads

      if (it + 1 < nIter) {
        const int nxt = cur ^ 1;
        const int knxt = key0 + 64;
#pragma unroll
        for (int i = 0; i < 2; ++i) {
          int chunk = wave * 2 + i;
          int sc = (chunk & 1) ? scK1 : scK0;
          async_copy16(Kh + (size_t)(knxt + chunk * 4 + srK) * HD + sc, &Ks[nxt][chunk * 512]);
        }
#pragma unroll
        for (int i = 0; i < 2; ++i) {
          int chunk = wave * 2 + i;
          async_copy16(Vh + (size_t)(chunk * 8 + srV) * TT + knxt + scV, &Vs[nxt][chunk * 512]);
        }
      }

      // S = Q K^T
      f32x4 s[4] = {};
#pragma unroll
      for (int kc = 0; kc < 4; ++kc) {
        const int koff = (kc * 32 + quad * 8) ^ swz;
#pragma unroll
        for (int kt = 0; kt < 4; ++kt) {
          bf16x8 kf = *(const bf16x8*)&Ks[cur][(kt * 16 + l16) * 128 + koff];
          s[kt] = __builtin_amdgcn_mfma_f32_16x16x32_bf16(qf[kc], kf, s[kt], 0, 0, 0);
        }
      }

      // exp(scale*s) with causal mask; accumulate per-lane l; P -> LDS (XOR)
      {
        bf16_t* pl = &Pl[wave][0];
#pragma unroll
        for (int r = 0; r < 4; ++r) {
          int prow = quad * 4 + r;
          int rel = q0 + prow - key0;  // cols <= rel survive
          int rbase = prow * 64;
          int sw = (prow & 7) << 3;
          float lr = 0.f;
#pragma unroll
          for (int kt = 0; kt < 4; ++kt) {
            int c16 = kt * 16 + l16;
            float e = (c16 > rel) ? 0.f : __expf(s[kt][r] * scale);
            lr += e;
            pl[rbase + (c16 ^ sw)] = (bf16_t)e;
          }
          l_i[r] += lr;
        }
      }

      // PV
      bf16x8 pf0 = *(const bf16x8*)&Pl[wave][l16 * 64 + ((quad * 8) ^ psw)];
      bf16x8 pf1 = *(const bf16x8*)&Pl[wave][l16 * 64 + ((32 + quad * 8) ^ psw)];
      const int voff0 = (quad * 8) ^ swz;
      const int voff1 = (32 + quad * 8) ^ swz;
#pragma unroll
      for (int n = 0; n < 8; ++n) {
        bf16x8 vf0 = *(const bf16x8*)&Vs[cur][(n * 16 + l16) * 64 + voff0];
        bf16x8 vf1 = *(const bf16x8*)&Vs[cur][(n * 16 + l16) * 64 + voff1];
        o[n] = __builtin_amdgcn_mfma_f32_16x16x32_bf16(pf0, vf0, o[n], 0, 0, 0);
        o[n] = __builtin_amdgcn_mfma_f32_16x16x32_bf16(pf1, vf1, o[n], 0, 0, 0);
      }
    }

    // reduce l across the 16-lane row group (one butterfly, once per tile)
#pragma unroll
    for (int r = 0; r < 4; ++r) {
      float l = l_i[r];
#pragma unroll
      for (int off = 1; off < 16; off <<= 1) l += __shfl_xor(l, off);
      l_i[r] = 1.f / l;
    }

#pragma unroll
    for (int n = 0; n < 8; ++n)
#pragma unroll
      for (int r = 0; r < 4; ++r) {
        int qg = q0 + quad * 4 + r;
        size_t off = ((size_t)(b * TT + qg) * CC) + h * HD + n * 16 + l16;
        Out[off] = (bf16_t)(o[n][r] * l_i[r]);
      }
  }
}

extern "C" void kernel_launch(void* const* d_in, const int* in_sizes, int n_in,
                              void* d_out, int out_size, void* d_ws, size_t ws_size,
                              hipStream_t stream) {
  const float* x    = (const float*)d_in[0];
  const float* cosT = (const float*)d_in[1];
  const float* sinT = (const float*)d_in[2];
  // d_in[3] = mask (unused; causal pattern is hard-coded)
  const float* Wq = (const float*)d_in[4];
  const float* Wk = (const float*)d_in[5];
  const float* Wv = (const float*)d_in[6];
  const float* Wo = (const float*)d_in[7];
  float* out = (float*)d_out;

  char* ws = (char*)d_ws;
  const size_t XSZ = (size_t)BB * TT * CC * 2;  // 16 MB (bf16)
  const size_t WSZ = (size_t)CC * CC * 2;       // 8 MB (bf16)
  bf16_t* x_bf  = (bf16_t*)(ws);
  bf16_t* wq_bf = (bf16_t*)(ws + XSZ);          // wq/wk/wv/wo contiguous
  bf16_t* wv_bf = (bf16_t*)(ws + XSZ + 2 * WSZ);
  bf16_t* wo_bf = (bf16_t*)(ws + XSZ + 3 * WSZ);
  bf16_t* Qb    = (bf16_t*)(ws + XSZ + 4 * WSZ);
  bf16_t* Kb    = (bf16_t*)(ws + 2 * XSZ + 4 * WSZ);
  bf16_t* Vt    = (bf16_t*)(ws + 3 * XSZ + 4 * WSZ);
  bf16_t* attn_bf = x_bf;  // x_bf dead after projections; alias saves 16 MB

  const int NX = BB * TT * CC;  // 8388608
  const int NW = CC * CC;       // 4194304
  cast_all<<<(NX / 4 + 4 * (NW / 4)) / 256, 256, 0, stream>>>(
      x, Wq, Wk, Wv, Wo, x_bf, wq_bf);

  // Q+K projection + fused RoPE: 256 blocks = one perfectly packed round
  (void)hipFuncSetAttribute(reinterpret_cast<const void*>(gemm_qkv256),
                            hipFuncAttributeMaxDynamicSharedMemorySize, 137216);
  gemm_qkv256<<<dim3(2 * CC / 256, BB * TT / 256), 512, 137216, stream>>>(
      x_bf, wq_bf, Qb, Kb, cosT, sinT, CC);

  // V projection: 128^2 tiles, 512 blocks (2+ blocks/CU, well balanced)
  gemm_v<<<dim3(CC / 128, BB * TT / 128), 256, 0, stream>>>(
      x_bf, wv_bf, Vt, CC);

  // balanced attention: 256 blocks x 512 threads (8 waves), 80KB LDS
  attn_kernel<<<dim3(BB * HH * 8), 512, 0, stream>>>(Qb, Kb, Vt, attn_bf);

  // Wo projection: 128x256 tiles, 256 blocks = one packed round
  (void)hipFuncSetAttribute(reinterpret_cast<const void*>(gemm_wo),
                            hipFuncAttributeMaxDynamicSharedMemorySize, 98304);
  gemm_wo<<<dim3(CC / 256, BB * TT / 128), 512, 98304, stream>>>(
      attn_bf, wo_bf, out, CC);
}